// Round 4
// baseline (428.950 us; speedup 1.0000x reference)
//
#include <hip/hip_runtime.h>
#include <stdint.h>

#define D_MODEL  4096
#define N_EXP    64
#define N_TOK    16384
#define MTILE    16            // tokens per block (one 16-row MFMA tile)
#define KSTEP    32            // k per 3-MFMA split step
#define KQ       1024          // K-quarter per wave (D_MODEL/4)
#define NSTEP    (KQ / KSTEP)  // 32 steps per wave

typedef float  f32x4  __attribute__((ext_vector_type(4)));
typedef short  bf16x8 __attribute__((ext_vector_type(8)));

// Split 8 fp32 into bf16 hi (RNE) + bf16 lo (truncated residual).
// Validated in R3 (absmax 3.9e-3): logits = hi*hi + hi*lo + lo*hi.
__device__ __forceinline__ void cvt8(float4 v0, float4 v1, bf16x8& hi, bf16x8& lo) {
  float f[8] = {v0.x, v0.y, v0.z, v0.w, v1.x, v1.y, v1.z, v1.w};
#pragma unroll
  for (int i = 0; i < 8; ++i) {
    unsigned u  = __builtin_bit_cast(unsigned, f[i]);
    unsigned r  = u + 0x7FFFu + ((u >> 16) & 1u);     // RNE to bf16
    unsigned hb = r & 0xFFFF0000u;                    // hi as f32 bits
    float    res = f[i] - __builtin_bit_cast(float, hb);  // exact (Sterbenz)
    hi[i] = (short)(hb >> 16);
    lo[i] = (short)(__builtin_bit_cast(unsigned, res) >> 16);
  }
}

__global__ __launch_bounds__(256) void SimpleMoERouter_54219667144993_kernel(
    const float* __restrict__ X, const float* __restrict__ W,
    float* __restrict__ outw, float* __restrict__ outi)
{
  // Per-wave K-quarter partial logits; reduced once at the end.
  __shared__ float sRed[4][MTILE][N_EXP + 4];   // +4 pad: 2-way banks (free)

  const int tid  = threadIdx.x;
  const int lane = tid & 63;
  const int wv   = tid >> 6;          // wave id = K-quarter id
  const int tok0 = blockIdx.x * MTILE;
  const int r16  = lane & 15;         // MFMA A-row / B-col
  const int kq   = lane >> 4;         // MFMA k-quad: k = kq*8 + j

  // Direct global fragment pointers (no LDS staging; X is streamed,
  // W (1 MiB) is L2-resident). 128 B contiguous consumed per row per step.
  const float* xp = X + (size_t)(tok0 + r16) * D_MODEL + wv * KQ + kq * 8;
  const float* wp = W + (size_t)r16 * D_MODEL + wv * KQ + kq * 8;

  f32x4 acc[4] = {{0.f,0.f,0.f,0.f},{0.f,0.f,0.f,0.f},
                  {0.f,0.f,0.f,0.f},{0.f,0.f,0.f,0.f}};

  // X prefetched one step ahead (HBM ~900 cyc); W on demand (L2 ~200 cyc,
  // hidden by 4 waves/SIMD TLP).
  float4 xa = *(const float4*)xp;
  float4 xb = *(const float4*)(xp + 4);

  for (int s = 0; s < NSTEP; ++s) {
    const int off = s * KSTEP;
    float4 nxa, nxb;
    if (s + 1 < NSTEP) {
      nxa = *(const float4*)(xp + off + KSTEP);
      nxb = *(const float4*)(xp + off + KSTEP + 4);
    }
    bf16x8 ah, al;
    cvt8(xa, xb, ah, al);
#pragma unroll
    for (int nt = 0; nt < 4; ++nt) {
      const float* wq = wp + (size_t)(nt * 16) * D_MODEL + off;
      float4 wa = *(const float4*)wq;
      float4 wb = *(const float4*)(wq + 4);
      bf16x8 bh, bl;
      cvt8(wa, wb, bh, bl);
      acc[nt] = __builtin_amdgcn_mfma_f32_16x16x32_bf16(ah, bh, acc[nt], 0, 0, 0);
      acc[nt] = __builtin_amdgcn_mfma_f32_16x16x32_bf16(ah, bl, acc[nt], 0, 0, 0);
      acc[nt] = __builtin_amdgcn_mfma_f32_16x16x32_bf16(al, bh, acc[nt], 0, 0, 0);
    }
    xa = nxa; xb = nxb;
  }

  // C/D layout (verified m89/m91): col = lane&15 (expert), row = kq*4 + reg.
#pragma unroll
  for (int nt = 0; nt < 4; ++nt) {
#pragma unroll
    for (int r = 0; r < 4; ++r) {
      sRed[wv][kq * 4 + r][nt * 16 + r16] = acc[nt][r];
    }
  }
  __syncthreads();

  // Top-2 + softmax: one thread per token, summing the 4 K-quarter partials.
  if (tid < MTILE) {
    float best = -3.4e38f, sec = -3.4e38f;
    int bi = 0, si = 0;
#pragma unroll 8
    for (int e = 0; e < N_EXP; ++e) {
      const float v = sRed[0][tid][e] + sRed[1][tid][e]
                    + sRed[2][tid][e] + sRed[3][tid][e];
      const bool b1 = v > best;   // strict > keeps earliest index on ties
      const bool b2 = v > sec;
      sec  = b1 ? best : (b2 ? v : sec);
      si   = b1 ? bi   : (b2 ? e : si);
      best = b1 ? v : best;
      bi   = b1 ? e : bi;
    }
    const float ed  = expf(sec - best);
    const float inv = 1.0f / (1.0f + ed);
    const int gt = tok0 + tid;
    outw[2 * gt]     = inv;         // softmax of [best, sec]
    outw[2 * gt + 1] = ed * inv;
    // Indices as float VALUES (harness reads whole d_out as f32) — R1 lesson.
    outi[2 * gt]     = (float)bi;
    outi[2 * gt + 1] = (float)si;
  }
}

extern "C" void kernel_launch(void* const* d_in, const int* in_sizes, int n_in,
                              void* d_out, int out_size, void* d_ws, size_t ws_size,
                              hipStream_t stream) {
  const float* X = (const float*)d_in[0];
  const float* W = (const float*)d_in[1];
  float* outw = (float*)d_out;
  float* outi = (float*)d_out + (size_t)N_TOK * 2;
  hipLaunchKernelGGL(SimpleMoERouter_54219667144993_kernel,
                     dim3(N_TOK / MTILE), dim3(256), 0, stream,
                     X, W, outw, outi);
}

// Round 9
// 420.430 us; speedup vs baseline: 1.0203x; 1.0203x over previous
//
#include <hip/hip_runtime.h>
#include <stdint.h>

#define D_MODEL 4096
#define N_EXP   64
#define N_TOK   16384
#define MTILE   32
#define KC      128
#define NCHUNK  (D_MODEL / KC)

typedef float  f32x4  __attribute__((ext_vector_type(4)));
typedef short  bf16x8 __attribute__((ext_vector_type(8)));

// Split 8 fp32 into bf16 hi (RNE) + bf16 lo (truncated residual).
// Validated R3/R4 (absmax 3.9e-3): logits = hi*hi + hi*lo + lo*hi.
__device__ __forceinline__ void cvt8(float4 v0, float4 v1, bf16x8& hi, bf16x8& lo) {
  float f[8] = {v0.x, v0.y, v0.z, v0.w, v1.x, v1.y, v1.z, v1.w};
#pragma unroll
  for (int i = 0; i < 8; ++i) {
    unsigned u  = __builtin_bit_cast(unsigned, f[i]);
    unsigned r  = u + 0x7FFFu + ((u >> 16) & 1u);     // RNE to bf16
    unsigned hb = r & 0xFFFF0000u;                    // hi as f32 bits
    float    res = f[i] - __builtin_bit_cast(float, hb);  // exact (Sterbenz)
    hi[i] = (short)(hb >> 16);
    lo[i] = (short)(__builtin_bit_cast(unsigned, res) >> 16);
  }
}

// ---- prep: split W once into packed bf16 hi/lo, MFMA-B-fragment order ----
// Wh[(kg*64 + e)*8 + j] = bf16_hi(W[e][kg*8 + j]), kg = 0..511. A wave's
// B-frag load (lanes: e=0..15 contiguous, kq strided) is 4x256B segments.
__global__ __launch_bounds__(256) void prep_w_kernel(
    const float* __restrict__ W, short* __restrict__ Wh, short* __restrict__ Wl)
{
  const int t  = blockIdx.x * 256 + threadIdx.x;   // 32768 threads
  const int e  = t & 63;
  const int kg = t >> 6;
  const float* src = W + (size_t)e * D_MODEL + kg * 8;
  float4 a = *(const float4*)src;
  float4 b = *(const float4*)(src + 4);
  bf16x8 hi, lo;
  cvt8(a, b, hi, lo);
  *(bf16x8*)(Wh + ((size_t)kg * 64 + e) * 8) = hi;   // consecutive t -> contiguous 16B
  *(bf16x8*)(Wl + ((size_t)kg * 64 + e) * 8) = lo;
}

// ---- main: X via async global_load_lds (coalesced, deep MLP), W from L2 ----
__global__ __launch_bounds__(256) void SimpleMoERouter_54219667144993_kernel(
    const float* __restrict__ X, const short* __restrict__ Wh,
    const short* __restrict__ Wl, float* __restrict__ outw, float* __restrict__ outi)
{
  __shared__ uint4 sX[2][MTILE * KC / 4];      // 2 x 16 KB, 16B granules [row][32]
  __shared__ float sRed[MTILE][N_EXP + 1];     // +1 pad: conflict-free scan

  const int tid  = threadIdx.x;
  const int lane = tid & 63;
  const int wv   = tid >> 6;
  const int tok0 = blockIdx.x * MTILE;
  const int r16  = lane & 15;
  const int kq   = lane >> 4;
  const int mh   = wv & 1;                     // token half
  const int nh   = wv >> 1;                    // expert half
  const int arow = mh * 16 + r16;              // A-frag token row in tile
  const int rs   = arow & 15;                  // granule-col XOR swizzle key

  const float* xbase = X + (size_t)tok0 * D_MODEL;

  // G21 both-sides swizzle: LDS dest linear (granule G), global SOURCE column
  // pre-swizzled (col ^ row&15); reads apply the same XOR -> even bank spread.
  auto STAGE = [&](int c, int b) {
#pragma unroll
    for (int q = 0; q < 4; ++q) {
      const int G   = q * 256 + tid;           // granule 0..1023
      const int row = G >> 5;                  // 32 granules per 128-f32 row
      const int col = G & 31;
      const int sc  = col ^ (row & 15);
      const float* src = xbase + (size_t)row * D_MODEL + (size_t)c * KC + sc * 4;
      __builtin_amdgcn_global_load_lds(
          (const __attribute__((address_space(1))) void*)src,
          (__attribute__((address_space(3))) void*)&sX[b][q * 256 + wv * 64],
          16, 0, 0);                           // wave-uniform base + lane*16
    }
  };

  f32x4 acc[2] = {{0.f,0.f,0.f,0.f},{0.f,0.f,0.f,0.f}};

  STAGE(0, 0);
  __syncthreads();                              // vmcnt(0) drain + barrier

  int b = 0;
  for (int c = 0; c < NCHUNK; ++c) {
    if (c + 1 < NCHUNK) STAGE(c + 1, b ^ 1);   // issue next chunk, fly under compute
#pragma unroll
    for (int s = 0; s < 4; ++s) {
      const int cg = s * 8 + kq * 2;           // original granule col (even)
      uint4 g0 = sX[b][arow * 32 + (cg ^ rs)];
      uint4 g1 = sX[b][arow * 32 + ((cg + 1) ^ rs)];
      bf16x8 ah, al;
      cvt8(__builtin_bit_cast(float4, g0), __builtin_bit_cast(float4, g1), ah, al);
      const size_t wg = ((size_t)c * 16 + s * 4 + kq) * 64;
#pragma unroll
      for (int j = 0; j < 2; ++j) {
        const size_t wi = (wg + (size_t)(nh * 2 + j) * 16 + r16) * 8;
        bf16x8 bh = *(const bf16x8*)(Wh + wi);
        bf16x8 bl = *(const bf16x8*)(Wl + wi);
        acc[j] = __builtin_amdgcn_mfma_f32_16x16x32_bf16(ah, bh, acc[j], 0, 0, 0);
        acc[j] = __builtin_amdgcn_mfma_f32_16x16x32_bf16(ah, bl, acc[j], 0, 0, 0);
        acc[j] = __builtin_amdgcn_mfma_f32_16x16x32_bf16(al, bh, acc[j], 0, 0, 0);
      }
    }
    __syncthreads();     // drains next-chunk DMA (had compute-time to fly) + frees buf
    b ^= 1;
  }

  // C/D layout (verified m89/m91): col = lane&15 (expert), row = kq*4 + reg (token)
#pragma unroll
  for (int j = 0; j < 2; ++j)
#pragma unroll
    for (int r = 0; r < 4; ++r)
      sRed[mh * 16 + kq * 4 + r][nh * 32 + j * 16 + r16] = acc[j][r];
  __syncthreads();

  // Top-2 + softmax: one thread per token
  if (tid < MTILE) {
    float best = -3.4e38f, sec = -3.4e38f;
    int bi = 0, si = 0;
#pragma unroll 8
    for (int e = 0; e < N_EXP; ++e) {
      const float v = sRed[tid][e];
      const bool b1 = v > best;   // strict > keeps earliest index on ties
      const bool b2 = v > sec;
      sec  = b1 ? best : (b2 ? v : sec);
      si   = b1 ? bi   : (b2 ? e : si);
      best = b1 ? v : best;
      bi   = b1 ? e : bi;
    }
    const float ed  = expf(sec - best);
    const float inv = 1.0f / (1.0f + ed);
    const int gt = tok0 + tid;
    outw[2 * gt]     = inv;         // softmax of [best, sec]
    outw[2 * gt + 1] = ed * inv;
    // Indices as float VALUES (harness reads whole d_out as f32) — R1 lesson.
    outi[2 * gt]     = (float)bi;
    outi[2 * gt + 1] = (float)si;
  }
}

extern "C" void kernel_launch(void* const* d_in, const int* in_sizes, int n_in,
                              void* d_out, int out_size, void* d_ws, size_t ws_size,
                              hipStream_t stream) {
  const float* X = (const float*)d_in[0];
  const float* W = (const float*)d_in[1];
  float* outw = (float*)d_out;
  float* outi = (float*)d_out + (size_t)N_TOK * 2;
  short* Wh = (short*)d_ws;                         // 512 KB
  short* Wl = (short*)d_ws + (size_t)N_EXP * D_MODEL;  // next 512 KB

  hipLaunchKernelGGL(prep_w_kernel, dim3(128), dim3(256), 0, stream, W, Wh, Wl);
  hipLaunchKernelGGL(SimpleMoERouter_54219667144993_kernel,
                     dim3(N_TOK / MTILE), dim3(256), 0, stream,
                     X, Wh, Wl, outw, outi);
}

// Round 12
// 364.703 us; speedup vs baseline: 1.1762x; 1.1528x over previous
//
#include <hip/hip_runtime.h>
#include <stdint.h>

#define D_MODEL 4096
#define N_EXP   64
#define N_TOK   16384
#define MTILE   32
#define KC      128
#define NCHUNK  (D_MODEL / KC)

typedef float  f32x4  __attribute__((ext_vector_type(4)));
typedef short  bf16x8 __attribute__((ext_vector_type(8)));

// Split 8 fp32 into bf16 hi (RNE) + bf16 lo (truncated residual).
// Validated R3/R9 (absmax 3.9e-3): logits = hi*hi + hi*lo + lo*hi.
__device__ __forceinline__ void cvt8(float4 v0, float4 v1, bf16x8& hi, bf16x8& lo) {
  float f[8] = {v0.x, v0.y, v0.z, v0.w, v1.x, v1.y, v1.z, v1.w};
#pragma unroll
  for (int i = 0; i < 8; ++i) {
    unsigned u  = __builtin_bit_cast(unsigned, f[i]);
    unsigned r  = u + 0x7FFFu + ((u >> 16) & 1u);     // RNE to bf16
    unsigned hb = r & 0xFFFF0000u;                    // hi as f32 bits
    float    res = f[i] - __builtin_bit_cast(float, hb);  // exact (Sterbenz)
    hi[i] = (short)(hb >> 16);
    lo[i] = (short)(__builtin_bit_cast(unsigned, res) >> 16);
  }
}

// ---- prep: split W once into packed bf16 hi/lo, MFMA-B-fragment order ----
// Wh[(kg*64 + e)*8 + j] = bf16_hi(W[e][kg*8 + j]), kg = 0..511.
__global__ __launch_bounds__(256) void prep_w_kernel(
    const float* __restrict__ W, short* __restrict__ Wh, short* __restrict__ Wl)
{
  const int t  = blockIdx.x * 256 + threadIdx.x;   // 32768 threads
  const int e  = t & 63;
  const int kg = t >> 6;
  const float* src = W + (size_t)e * D_MODEL + kg * 8;
  float4 a = *(const float4*)src;
  float4 b = *(const float4*)(src + 4);
  bf16x8 hi, lo;
  cvt8(a, b, hi, lo);
  *(bf16x8*)(Wh + ((size_t)kg * 64 + e) * 8) = hi;
  *(bf16x8*)(Wl + ((size_t)kg * 64 + e) * 8) = lo;
}

// Prefetch one chunk's W fragments (16 x bf16x8 = 64 VGPR) — issued at body
// top, consumed one body later: L2 latency hides under current-chunk MFMAs.
// Macro (not lambda) so the dst array never escapes -> stays in registers.
#define LOADW(dst, c) do {                                              \
  _Pragma("unroll")                                                     \
  for (int t_ = 0; t_ < 8; ++t_) {                                      \
    const size_t wg_ = ((size_t)(c) * 16 + (t_ >> 1) * 4 + kq) * 64;    \
    const size_t wi_ = (wg_ + (size_t)(nh * 2 + (t_ & 1)) * 16 + r16) * 8; \
    dst[2 * t_]     = *(const bf16x8*)(Wh + wi_);                       \
    dst[2 * t_ + 1] = *(const bf16x8*)(Wl + wi_);                       \
  } } while (0)

#define COMPUTE(bb, w) do {                                             \
  _Pragma("unroll")                                                     \
  for (int s_ = 0; s_ < 4; ++s_) {                                      \
    const int cg_ = s_ * 8 + kq * 2;                                    \
    uint4 g0_ = sX[bb][arow * 32 + (cg_ ^ rs)];                         \
    uint4 g1_ = sX[bb][arow * 32 + ((cg_ + 1) ^ rs)];                   \
    bf16x8 ah_, al_;                                                    \
    cvt8(__builtin_bit_cast(float4, g0_), __builtin_bit_cast(float4, g1_), ah_, al_); \
    _Pragma("unroll")                                                   \
    for (int j_ = 0; j_ < 2; ++j_) {                                    \
      acc[j_] = __builtin_amdgcn_mfma_f32_16x16x32_bf16(ah_, w[2*(s_*2+j_)],   acc[j_], 0, 0, 0); \
      acc[j_] = __builtin_amdgcn_mfma_f32_16x16x32_bf16(ah_, w[2*(s_*2+j_)+1], acc[j_], 0, 0, 0); \
      acc[j_] = __builtin_amdgcn_mfma_f32_16x16x32_bf16(al_, w[2*(s_*2+j_)],   acc[j_], 0, 0, 0); \
    } } } while (0)

// ---- main: X via async global_load_lds, W register-pipelined from L2 ----
__global__ __launch_bounds__(256, 2) void SimpleMoERouter_54219667144993_kernel(
    const float* __restrict__ X, const short* __restrict__ Wh,
    const short* __restrict__ Wl, float* __restrict__ outw, float* __restrict__ outi)
{
  __shared__ uint4 sX[2][MTILE * KC / 4];      // 2 x 16 KB, 16B granules [row][32]
  __shared__ float sRed[MTILE][N_EXP + 1];     // +1 pad: conflict-free scan

  const int tid  = threadIdx.x;
  const int lane = tid & 63;
  const int wv   = tid >> 6;
  const int tok0 = blockIdx.x * MTILE;
  const int r16  = lane & 15;
  const int kq   = lane >> 4;
  const int mh   = wv & 1;                     // token half
  const int nh   = wv >> 1;                    // expert half
  const int arow = mh * 16 + r16;              // A-frag token row in tile
  const int rs   = arow & 15;                  // granule-col XOR swizzle key

  const float* xbase = X + (size_t)tok0 * D_MODEL;

  // G21 both-sides swizzle: LDS dest linear, global SOURCE column pre-swizzled.
  auto STAGE = [&](int c, int b) {
#pragma unroll
    for (int q = 0; q < 4; ++q) {
      const int G   = q * 256 + tid;           // granule 0..1023
      const int row = G >> 5;
      const int col = G & 31;
      const int sc  = col ^ (row & 15);
      const float* src = xbase + (size_t)row * D_MODEL + (size_t)c * KC + sc * 4;
      __builtin_amdgcn_global_load_lds(
          (const __attribute__((address_space(1))) void*)src,
          (__attribute__((address_space(3))) void*)&sX[b][q * 256 + wv * 64],
          16, 0, 0);
    }
  };

  f32x4 acc[2] = {{0.f,0.f,0.f,0.f},{0.f,0.f,0.f,0.f}};
  bf16x8 wA[16], wB[16];                       // double-buffered W fragments

  LOADW(wA, 0);
  STAGE(0, 0);
  __syncthreads();                              // drain + barrier

  // Chunk loop unrolled x2: all register indices static (rule #20).
  for (int c = 0; c < NCHUNK; c += 2) {
    // body A: prefetch c+1 (DMA + W regs), compute chunk c
    STAGE(c + 1, 1);                            // NCHUNK even: c+1 < NCHUNK always
    LOADW(wB, c + 1);
    COMPUTE(0, wA);
    __syncthreads();
    // body B: prefetch c+2, compute chunk c+1
    if (c + 2 < NCHUNK) {
      STAGE(c + 2, 0);
      LOADW(wA, c + 2);
    }
    COMPUTE(1, wB);
    __syncthreads();
  }

  // C/D layout (verified m89/m91): col = lane&15 (expert), row = kq*4 + reg
#pragma unroll
  for (int j = 0; j < 2; ++j)
#pragma unroll
    for (int r = 0; r < 4; ++r)
      sRed[mh * 16 + kq * 4 + r][nh * 32 + j * 16 + r16] = acc[j][r];
  __syncthreads();

  // Top-2 + softmax: one thread per token
  if (tid < MTILE) {
    float best = -3.4e38f, sec = -3.4e38f;
    int bi = 0, si = 0;
#pragma unroll 8
    for (int e = 0; e < N_EXP; ++e) {
      const float v = sRed[tid][e];
      const bool b1 = v > best;   // strict > keeps earliest index on ties
      const bool b2 = v > sec;
      sec  = b1 ? best : (b2 ? v : sec);
      si   = b1 ? bi   : (b2 ? e : si);
      best = b1 ? v : best;
      bi   = b1 ? e : bi;
    }
    const float ed  = expf(sec - best);
    const float inv = 1.0f / (1.0f + ed);
    const int gt = tok0 + tid;
    outw[2 * gt]     = inv;         // softmax of [best, sec]
    outw[2 * gt + 1] = ed * inv;
    // Indices as float VALUES (harness reads whole d_out as f32) — R1 lesson.
    outi[2 * gt]     = (float)bi;
    outi[2 * gt + 1] = (float)si;
  }
}

extern "C" void kernel_launch(void* const* d_in, const int* in_sizes, int n_in,
                              void* d_out, int out_size, void* d_ws, size_t ws_size,
                              hipStream_t stream) {
  const float* X = (const float*)d_in[0];
  const float* W = (const float*)d_in[1];
  float* outw = (float*)d_out;
  float* outi = (float*)d_out + (size_t)N_TOK * 2;
  short* Wh = (short*)d_ws;                         // 512 KB
  short* Wl = (short*)d_ws + (size_t)N_EXP * D_MODEL;  // next 512 KB

  hipLaunchKernelGGL(prep_w_kernel, dim3(128), dim3(256), 0, stream, W, Wh, Wl);
  hipLaunchKernelGGL(SimpleMoERouter_54219667144993_kernel,
                     dim3(N_TOK / MTILE), dim3(256), 0, stream,
                     X, Wh, Wl, outw, outi);
}